// Round 3
// baseline (461.269 us; speedup 1.0000x reference)
//
#include <hip/hip_runtime.h>

#define N_DATA     131072
#define D_VECTOR   128
#define N_SUB      8
#define D_SUB      16
#define N_CLUSTERS 256
#define N_CODEBOOKS 64
#define PMAX       (N_DATA + N_CODEBOOKS*128)   // padded perm capacity (139264)

typedef float v2f __attribute__((ext_vector_type(2)));

// ws layout in 4-byte words (~2.7 MB; cbT lives in d_out, overwritten by decode)
#define WS_LABELS 0
#define WS_PERM   (N_DATA)                      // padded perm: PMAX words
#define WS_CNT    (WS_PERM + PMAX)
#define WS_CURSOR (WS_CNT + 64)
#define WS_OFF    (WS_CURSOR + 64)              // 65 real exclusive offsets
#define WS_OFFP   (WS_OFF + 80)                 // 65 padded exclusive offsets
#define WS_CNORM  (WS_OFFP + 80)
#define WS_CNSEL  (WS_CNORM + N_CODEBOOKS*N_SUB*N_CLUSTERS)
#define WS_CODES  (WS_CNSEL + 64)               // 131072*8 bytes

// ---------------------------------------------------------------- precompute
// cnorm = np.sum(cb*cb, axis=2) (sequential d, separate mul/add), plus a
// pair-interleaved transposed codebook for the encode stage:
//   cbT[row][k>>1][d][k&1] = cb[row][d][k]   (row = l*8+s)
// so encode can s_load 32 consecutive floats per k-pair and feed v_pk ops.
__global__ __launch_bounds__(256) void pq_precompute(
    const float* __restrict__ cb, const float* __restrict__ sel,
    float* __restrict__ cnorm_cb, float* __restrict__ cnorm_sel,
    float* __restrict__ cbT, int* __restrict__ cnt)
{
    int row = blockIdx.x;                 // 0..511 = l*8+s
    int k   = threadIdx.x;                // 0..255
    const float* p  = cb  + (size_t)row * (D_SUB * N_CLUSTERS) + k;
    float*       ct = cbT + ((size_t)row << 12) + ((size_t)(k >> 1) << 5) + (k & 1);
    float sum = 0.f;
#pragma unroll
    for (int d = 0; d < D_SUB; d++) {
        float v = p[(size_t)d * N_CLUSTERS];
        ct[d << 1] = v;
        sum = __fadd_rn(sum, __fmul_rn(v, v));
    }
    int idx = row * 256 + k;
    cnorm_cb[idx] = sum;
    if (idx < N_CODEBOOKS) {
        float s2 = 0.f;
        for (int d = 0; d < D_VECTOR; d++) {
            float v = sel[d * N_CODEBOOKS + idx];
            s2 = __fadd_rn(s2, __fmul_rn(v, v));
        }
        cnorm_sel[idx] = s2;
        cnt[idx] = 0;
    }
}

// ---------------------------------------------------------------- stage 1: labels
__global__ __launch_bounds__(256, 4) void pq_labels2(
    const float* __restrict__ x, const float* __restrict__ sel,
    const float* __restrict__ cnorm_sel,
    int* __restrict__ labels, int* __restrict__ cnt)
{
    __shared__ int hist[N_CODEBOOKS];
    int tid = threadIdx.x;
    if (tid < N_CODEBOOKS) hist[tid] = 0;
    __syncthreads();

    int n = blockIdx.x * 256 + tid;

    v2f acc[32];
#pragma unroll
    for (int lp = 0; lp < 32; lp++) acc[lp] = (v2f){0.f, 0.f};

    float xn = 0.f;
    for (int d = 0; d < D_VECTOR; d++) {
        float xv = x[(size_t)d * N_DATA + n];        // coalesced
        xn = __fadd_rn(xn, __fmul_rn(xv, xv));       // sequential d: numpy-exact
        v2f xv2 = (v2f){xv, xv};
        const v2f* sp = (const v2f*)(sel + d * N_CODEBOOKS);  // uniform
#pragma unroll
        for (int lp = 0; lp < 32; lp++)
            acc[lp] = __builtin_elementwise_fma(xv2, sp[lp], acc[lp]);  // v_pk_fma_f32
    }

    float best = 1e30f;
    int   bl = 0;
#pragma unroll
    for (int lp = 0; lp < 32; lp++) {
        float dx = __fadd_rn(__fsub_rn(xn, __fmul_rn(2.0f, acc[lp].x)), cnorm_sel[2*lp]);
        float dy = __fadd_rn(__fsub_rn(xn, __fmul_rn(2.0f, acc[lp].y)), cnorm_sel[2*lp + 1]);
        if (dx < best) { best = dx; bl = 2*lp; }
        if (dy < best) { best = dy; bl = 2*lp + 1; }
    }
    labels[n] = bl;
    atomicAdd(&hist[bl], 1);
    __syncthreads();
    if (tid < N_CODEBOOKS) atomicAdd(&cnt[tid], hist[tid]);
}

// ---------------------------------------------------------------- scan (1 wave)
// Real exclusive scan (off) + 128-padded exclusive scan (offP); cursor = offP.
__global__ void pq_scan(const int* __restrict__ cnt, int* __restrict__ off,
                        int* __restrict__ offP, int* __restrict__ cursor)
{
    int tid = threadIdx.x;
    int v  = cnt[tid];
    int vp = (v + 127) & ~127;
    int iR = v, iP = vp;
#pragma unroll
    for (int sft = 1; sft < 64; sft <<= 1) {
        int oR = __shfl_up(iR, sft, 64);
        int oP = __shfl_up(iP, sft, 64);
        if (tid >= sft) { iR += oR; iP += oP; }
    }
    off[tid]    = iR - v;
    offP[tid]   = iP - vp;
    cursor[tid] = iP - vp;
    if (tid == 63) { off[64] = iR; offP[64] = iP; }
}

// ---------------------------------------------------------------- counting-sort scatter
// perm entries are PACKED: (n << 6) | label; cursor bases are PADDED offsets,
// so each segment's real entries occupy [offP[l], offP[l]+cnt[l]).
__global__ __launch_bounds__(256) void pq_scatter(
    const int* __restrict__ labels, int* __restrict__ cursor, unsigned int* __restrict__ perm)
{
    __shared__ int lcnt[N_CODEBOOKS];
    __shared__ int lbase[N_CODEBOOKS];
    int tid = threadIdx.x;
    if (tid < N_CODEBOOKS) lcnt[tid] = 0;
    __syncthreads();
    int base = blockIdx.x * 1024;
    int lv[4], slot[4];
#pragma unroll
    for (int i = 0; i < 4; i++) {
        int n = base + i * 256 + tid;
        int l = labels[n];
        lv[i] = l;
        slot[i] = atomicAdd(&lcnt[l], 1);
    }
    __syncthreads();
    if (tid < N_CODEBOOKS) lbase[tid] = atomicAdd(&cursor[tid], lcnt[tid]);
    __syncthreads();
#pragma unroll
    for (int i = 0; i < 4; i++) {
        int n = base + i * 256 + tid;
        perm[lbase[lv[i]] + slot[i]] = ((unsigned)n << 6) | (unsigned)lv[i];
    }
}

// ---------------------------------------------------------------- pad fill
// Fill each segment's padded tail with its first real entry: every 128-aligned
// wave span in perm-space is then single-label, and filler lanes recompute a
// real point's code (identical arithmetic -> identical byte; duplicate writes
// are benign). One block per label.
__global__ void pq_fill(const int* __restrict__ cnt, const int* __restrict__ offP,
                        unsigned int* __restrict__ perm)
{
    int l = blockIdx.x;
    int c = cnt[l];
    if (c == 0) return;
    int base = offP[l];
    int end  = base + ((c + 127) & ~127);
    unsigned seed = perm[base];
    for (int p = base + c + (int)threadIdx.x; p < end; p += 64) perm[p] = seed;
}

// ---------------------------------------------------------------- stage 2: PQ encode v7
// Wave = 128 consecutive padded perm positions (2 points per lane), statically
// single-label thanks to padding -> no ballot/readlane multipass. Codebook is
// a wave-uniform s_load stream (one stream feeds 2 points: half the scalar
// traffic of v6, 2x the per-wave ILP). Arithmetic per (point,k) is unchanged:
// sequential-d separate mul/add (contract off), dist = (xn - 2*acc) + cn.
// Argmin: per-component chains (even-k slot x, odd-k slot y), ascending kkp
// with strict < (first-occurrence per chain), merged with an exact lower-k
// tie rule -> numpy first-occurrence overall. Distances are NaN-free.
__global__ __launch_bounds__(256, 4) void pq_encode8(
    const float* __restrict__ x, const float* __restrict__ cbT,
    const float* __restrict__ cnorm_cb, const unsigned int* __restrict__ perm,
    const int* __restrict__ offP, unsigned char* __restrict__ codes)
{
    int tid  = threadIdx.x;
    int lane = tid & 63;
    int w    = tid >> 6;
    int s    = blockIdx.x & 7;
    int base = (int)(blockIdx.x >> 3) * 512 + w * 128;
    int Ptot = offP[64];                        // uniform
    if (base >= Ptot) return;                   // Ptot and base are multiples of 128

    unsigned pk0 = perm[base + lane];
    unsigned pk1 = perm[base + 64 + lane];
    int l  = __builtin_amdgcn_readfirstlane((int)pk0) & 63;   // uniform by construction
    int n0 = (int)(pk0 >> 6), n1 = (int)(pk1 >> 6);

    // gather subvector components from x [d][n] (setup cost, amortized over the scan)
    v2f xs0[D_SUB], xs1[D_SUB];
#pragma unroll
    for (int d = 0; d < D_SUB; d++) {
        float a = x[(size_t)(s * D_SUB + d) * N_DATA + n0];
        float b = x[(size_t)(s * D_SUB + d) * N_DATA + n1];
        xs0[d] = (v2f){a, a};
        xs1[d] = (v2f){b, b};
    }

    // xnorm: numpy strided reduction (sequential d, separate mul/add)
    float xn0 = 0.f, xn1 = 0.f;
#pragma unroll
    for (int d = 0; d < D_SUB; d++) {
        xn0 = __fadd_rn(xn0, __fmul_rn(xs0[d].x, xs0[d].x));
        xn1 = __fadd_rn(xn1, __fmul_rn(xs1[d].x, xs1[d].x));
    }
    const v2f xnv0 = (v2f){xn0, xn0}, xnv1 = (v2f){xn1, xn1};
    const v2f twov = (v2f){2.f, 2.f};

    const float* cbs = cbT      + ((size_t)(l * N_SUB + s) << 12);  // uniform -> s_load
    const float* cns = cnorm_cb + ((size_t)(l * N_SUB + s) << 8);   // uniform -> s_load

    float b0x = 1e30f, b0y = 1e30f, b1x = 1e30f, b1y = 1e30f;
    int   k0x = 0, k0y = 0, k1x = 0, k1y = 0;
    {
#pragma clang fp contract(off)
#pragma unroll 2
        for (int kkp = 0; kkp < N_CLUSTERS / 2; kkp++) {
            const v2f* cp  = (const v2f*)(cbs + (kkp << 5));  // 32 floats: k-pair x 16 d
            v2f cn2 = *(const v2f*)(cns + (kkp << 1));
            v2f a0 = (v2f){0.f, 0.f}, a1 = (v2f){0.f, 0.f};
#pragma unroll
            for (int d = 0; d < D_SUB; d++) {
                v2f c = cp[d];
                a0 = a0 + xs0[d] * c;          // v_pk_mul + v_pk_add, exact order
                a1 = a1 + xs1[d] * c;
            }
            v2f d0 = (xnv0 - twov * a0) + cn2;
            v2f d1 = (xnv1 - twov * a1) + cn2;
            if (d0.x < b0x) { b0x = d0.x; k0x = kkp; }
            if (d0.y < b0y) { b0y = d0.y; k0y = kkp; }
            if (d1.x < b1x) { b1x = d1.x; k1x = kkp; }
            if (d1.y < b1y) { b1y = d1.y; k1y = kkp; }
        }
    }
    // merge even/odd chains: strictly-better or equal-with-lower-k picks odd
    int bk0 = 2 * k0x;
    { int ky = 2 * k0y + 1; if (b0y < b0x || (b0y == b0x && ky < bk0)) bk0 = ky; }
    int bk1 = 2 * k1x;
    { int ky = 2 * k1y + 1; if (b1y < b1x || (b1y == b1x && ky < bk1)) bk1 = ky; }

    codes[((size_t)n0 << 3) | s] = (unsigned char)bk0;
    codes[((size_t)n1 << 3) | s] = (unsigned char)bk1;
}

// ---------------------------------------------------------------- decode: coalesced out writes
__global__ __launch_bounds__(256) void pq_decode(
    const float* __restrict__ cb, const int* __restrict__ labels,
    const unsigned char* __restrict__ codes, float* __restrict__ out)
{
    int s = blockIdx.x & 7;
    int n = (blockIdx.x >> 3) * 256 + threadIdx.x;
    int l = labels[n];
    int k = codes[(size_t)n * N_SUB + s];
    const float* base = cb + ((size_t)(l * N_SUB + s) * D_SUB) * N_CLUSTERS + k;
#pragma unroll
    for (int dd = 0; dd < D_SUB; dd++)
        out[(size_t)(s * D_SUB + dd) * N_DATA + n] = base[(size_t)dd * N_CLUSTERS];
}

// ---------------------------------------------------------------- launcher
extern "C" void kernel_launch(void* const* d_in, const int* in_sizes, int n_in,
                              void* d_out, int out_size, void* d_ws, size_t ws_size,
                              hipStream_t stream)
{
    (void)in_sizes; (void)n_in; (void)out_size; (void)ws_size;
    const float* x   = (const float*)d_in[0];
    const float* cb  = (const float*)d_in[1];
    const float* sel = (const float*)d_in[2];
    float* out = (float*)d_out;

    int*   wsi    = (int*)d_ws;
    float* wsf    = (float*)d_ws;
    int*   labels = wsi + WS_LABELS;
    unsigned int* perm = (unsigned int*)(wsi + WS_PERM);
    int*   cnt    = wsi + WS_CNT;
    int*   cursor = wsi + WS_CURSOR;
    int*   off    = wsi + WS_OFF;
    int*   offP   = wsi + WS_OFFP;
    float* cnorm  = wsf + WS_CNORM;
    float* cnsel  = wsf + WS_CNSEL;
    unsigned char* codes = (unsigned char*)(wsi + WS_CODES);

    // transposed pair-interleaved codebook (8 MB) lives in d_out; pq_decode
    // fully overwrites d_out afterwards.
    float* cbT = out;

    hipLaunchKernelGGL(pq_precompute, dim3(512), dim3(256), 0, stream, cb, sel, cnorm, cnsel, cbT, cnt);
    hipLaunchKernelGGL(pq_labels2, dim3(N_DATA / 256), dim3(256), 0, stream, x, sel, cnsel, labels, cnt);
    hipLaunchKernelGGL(pq_scan, dim3(1), dim3(64), 0, stream, cnt, off, offP, cursor);
    hipLaunchKernelGGL(pq_scatter, dim3(N_DATA / 1024), dim3(256), 0, stream, labels, cursor, perm);
    hipLaunchKernelGGL(pq_fill, dim3(N_CODEBOOKS), dim3(64), 0, stream, cnt, offP, perm);
    hipLaunchKernelGGL(pq_encode8, dim3((PMAX / 512) * N_SUB), dim3(256), 0, stream,
                       x, cbT, cnorm, perm, offP, codes);
    hipLaunchKernelGGL(pq_decode, dim3((N_DATA / 256) * N_SUB), dim3(256), 0, stream, cb, labels, codes, out);
}

// Round 4
// 430.249 us; speedup vs baseline: 1.0721x; 1.0721x over previous
//
#include <hip/hip_runtime.h>

#define N_DATA     131072
#define D_VECTOR   128
#define N_SUB      8
#define D_SUB      16
#define N_CLUSTERS 256
#define N_CODEBOOKS 64

typedef float v2f __attribute__((ext_vector_type(2)));

// ws layout in 4-byte words (~2.5 MB base; +8 MB optional cbT2 if ws permits).
// xg[s][dst][16] (permuted-gathered x, 64 MiB) lives in d_out until decode
// overwrites it.
#define WS_LABELS 0
#define WS_PERM   (N_DATA)
#define WS_CNT    (2*N_DATA)
#define WS_CURSOR (2*N_DATA + 64)
#define WS_OFF    (2*N_DATA + 128)
#define WS_CNORM  (2*N_DATA + 256)                  // 512 rows x 256 k, numpy-order fp32
#define WS_CNSEL  (WS_CNORM + N_CODEBOOKS*N_SUB*N_CLUSTERS)
#define WS_CODES  (WS_CNSEL + 64)                   // 131072*8 bytes = 262144 words
#define WS_CBT2   (WS_CODES + 262144)               // optional: row-major codebook for decode
#define CBT2_WORDS (N_CODEBOOKS*N_SUB*N_CLUSTERS*D_SUB)   // 2,097,152 words = 8 MiB

// ---------------------------------------------------------------- precompute
// cnorm = np.sum(cb*cb, axis=2) (sequential d, separate mul/add). If cbT2 is
// non-null, also emit a row-major codebook cbT2[row][k][d] = cb[row][d][k]
// (row = l*8+s) so decode reads ONE 64B line per (point,s) instead of a
// 16-element strided column.
__global__ __launch_bounds__(256) void pq_precompute(
    const float* __restrict__ cb, const float* __restrict__ sel,
    float* __restrict__ cnorm_cb, float* __restrict__ cnorm_sel,
    float* __restrict__ cbT2, int* __restrict__ cnt)
{
    int row = blockIdx.x;                 // 0..511 = l*8+s
    int k   = threadIdx.x;                // 0..255
    const float* p = cb + (size_t)row * (D_SUB * N_CLUSTERS) + k;
    float vals[D_SUB];
    float sum = 0.f;
#pragma unroll
    for (int d = 0; d < D_SUB; d++) {
        float v = p[(size_t)d * N_CLUSTERS];
        vals[d] = v;
        sum = __fadd_rn(sum, __fmul_rn(v, v));
    }
    int idx = row * 256 + k;
    cnorm_cb[idx] = sum;
    if (cbT2) {                           // uniform branch
        float4* dst = (float4*)(cbT2 + ((size_t)row << 12) + ((size_t)k << 4));
#pragma unroll
        for (int q = 0; q < 4; q++)
            dst[q] = make_float4(vals[4*q], vals[4*q+1], vals[4*q+2], vals[4*q+3]);
    }
    if (idx < N_CODEBOOKS) {
        float s2 = 0.f;
        for (int d = 0; d < D_VECTOR; d++) {
            float v = sel[d * N_CODEBOOKS + idx];
            s2 = __fadd_rn(s2, __fmul_rn(v, v));
        }
        cnorm_sel[idx] = s2;
        cnt[idx] = 0;
    }
}

// ---------------------------------------------------------------- stage 1: labels
__global__ __launch_bounds__(256, 4) void pq_labels2(
    const float* __restrict__ x, const float* __restrict__ sel,
    const float* __restrict__ cnorm_sel,
    int* __restrict__ labels, int* __restrict__ cnt)
{
    __shared__ int hist[N_CODEBOOKS];
    int tid = threadIdx.x;
    if (tid < N_CODEBOOKS) hist[tid] = 0;
    __syncthreads();

    int n = blockIdx.x * 256 + tid;

    v2f acc[32];
#pragma unroll
    for (int lp = 0; lp < 32; lp++) acc[lp] = (v2f){0.f, 0.f};

    float xn = 0.f;
    for (int d = 0; d < D_VECTOR; d++) {
        float xv = x[(size_t)d * N_DATA + n];        // coalesced
        xn = __fadd_rn(xn, __fmul_rn(xv, xv));       // sequential d: numpy-exact
        v2f xv2 = (v2f){xv, xv};
        const v2f* sp = (const v2f*)(sel + d * N_CODEBOOKS);  // uniform
#pragma unroll
        for (int lp = 0; lp < 32; lp++)
            acc[lp] = __builtin_elementwise_fma(xv2, sp[lp], acc[lp]);  // v_pk_fma_f32
    }

    float best = 1e30f;
    int   bl = 0;
#pragma unroll
    for (int lp = 0; lp < 32; lp++) {
        float dx = __fadd_rn(__fsub_rn(xn, __fmul_rn(2.0f, acc[lp].x)), cnorm_sel[2*lp]);
        float dy = __fadd_rn(__fsub_rn(xn, __fmul_rn(2.0f, acc[lp].y)), cnorm_sel[2*lp + 1]);
        if (dx < best) { best = dx; bl = 2*lp; }
        if (dy < best) { best = dy; bl = 2*lp + 1; }
    }
    labels[n] = bl;
    atomicAdd(&hist[bl], 1);
    __syncthreads();
    if (tid < N_CODEBOOKS) atomicAdd(&cnt[tid], hist[tid]);
}

// ---------------------------------------------------------------- scan (1 wave)
__global__ void pq_scan(const int* __restrict__ cnt, int* __restrict__ off, int* __restrict__ cursor)
{
    int tid = threadIdx.x;
    int v = cnt[tid];
    int inc = v;
#pragma unroll
    for (int sft = 1; sft < 64; sft <<= 1) {
        int o = __shfl_up(inc, sft, 64);
        if (tid >= sft) inc += o;
    }
    int exc = inc - v;
    off[tid] = exc;
    cursor[tid] = exc;
    if (tid == 63) off[64] = inc;
}

// ---------------------------------------------------------------- counting-sort scatter + permute-gather
// perm entries are PACKED: (n << 6) | label. Additionally copies each point's
// 8 subvectors into xg[s][dst][16] (exact fp32 copy): x reads are coalesced
// across threads (consecutive n), xg writes are dense scattered 64B lines.
// Encode then reads xg perfectly coalesced with zero gather.
__global__ __launch_bounds__(256) void pq_scatter(
    const float* __restrict__ x, const int* __restrict__ labels,
    int* __restrict__ cursor, unsigned int* __restrict__ perm,
    float* __restrict__ xg)
{
    __shared__ int lcnt[N_CODEBOOKS];
    __shared__ int lbase[N_CODEBOOKS];
    int tid = threadIdx.x;
    if (tid < N_CODEBOOKS) lcnt[tid] = 0;
    __syncthreads();
    int base = blockIdx.x * 1024;
    int lv[4], slot[4];
#pragma unroll
    for (int i = 0; i < 4; i++) {
        int n = base + i * 256 + tid;
        int l = labels[n];
        lv[i] = l;
        slot[i] = atomicAdd(&lcnt[l], 1);
    }
    __syncthreads();
    if (tid < N_CODEBOOKS) lbase[tid] = atomicAdd(&cursor[tid], lcnt[tid]);
    __syncthreads();
#pragma unroll
    for (int i = 0; i < 4; i++) {
        int n = base + i * 256 + tid;
        int dst = lbase[lv[i]] + slot[i];
        perm[dst] = ((unsigned)n << 6) | (unsigned)lv[i];
#pragma unroll
        for (int s = 0; s < N_SUB; s++) {
            float v[D_SUB];
#pragma unroll
            for (int d = 0; d < D_SUB; d++)
                v[d] = x[(size_t)(s * D_SUB + d) * N_DATA + n];   // coalesced
            float4* o = (float4*)(xg + (((size_t)s * N_DATA + (size_t)dst) << 4));
            o[0] = make_float4(v[0],  v[1],  v[2],  v[3]);
            o[1] = make_float4(v[4],  v[5],  v[6],  v[7]);
            o[2] = make_float4(v[8],  v[9],  v[10], v[11]);
            o[3] = make_float4(v[12], v[13], v[14], v[15]);
        }
    }
}

// ---------------------------------------------------------------- stage 2: PQ encode v8
// Lane = one point, in perm order: x reads from xg are fully coalesced (the
// v7 gather — 370 MB of HBM line traffic — is gone; scatter paid it once,
// densely). Codebook is streamed straight from cb via wave-uniform scalar
// loads (s_load_dwordx2 per d, stride 1KB; consecutive k-pairs re-hit the
// same 16 lines 8x -> scalar-cache friendly). Boundary waves (~3%) use the
// v6 ballot multipass. Arithmetic per (point,k) unchanged: sequential-d
// separate mul/add (contract off), dist = (xn - 2*acc) + cn. Argmin:
// per-component chains (even/odd k), ascending kkp strict <, merged with the
// exact lower-k tie rule -> numpy first-occurrence. Distances NaN-free.
__global__ __launch_bounds__(256, 8) void pq_encode9(
    const float* __restrict__ xg, const float* __restrict__ cb,
    const float* __restrict__ cnorm_cb, const unsigned int* __restrict__ perm,
    unsigned char* __restrict__ codes)
{
    int tid = threadIdx.x;
    int s   = blockIdx.x & 7;
    int pos = (int)(blockIdx.x >> 3) * 256 + tid;
    unsigned pk = perm[pos];
    int n = (int)(pk >> 6);
    int l = (int)(pk & 63u);

    const float4* xp = (const float4*)(xg + (((size_t)s * N_DATA + (size_t)pos) << 4));
    float4 x0 = xp[0], x1 = xp[1], x2 = xp[2], x3 = xp[3];
    float xs[D_SUB] = { x0.x, x0.y, x0.z, x0.w, x1.x, x1.y, x1.z, x1.w,
                        x2.x, x2.y, x2.z, x2.w, x3.x, x3.y, x3.z, x3.w };

    // xnorm: numpy strided reduction (sequential d, separate mul/add)
    float xn = 0.f;
#pragma unroll
    for (int d = 0; d < D_SUB; d++)
        xn = __fadd_rn(xn, __fmul_rn(xs[d], xs[d]));

    v2f xs2[D_SUB];
#pragma unroll
    for (int d = 0; d < D_SUB; d++) xs2[d] = (v2f){xs[d], xs[d]};
    const v2f xnv  = (v2f){xn, xn};
    const v2f twov = (v2f){2.f, 2.f};

    int bestk = 0;
    bool done = false;
    while (true) {
        unsigned long long todo = __ballot(!done);
        if (!todo) break;
        int src  = (int)(__ffsll((long long)todo) - 1);
        int lcur = __builtin_amdgcn_readlane(l, src);      // uniform label for this pass

        const float* cbs = cb       + ((size_t)(lcur * N_SUB + s) << 12);  // [d][k] row -> s_load
        const float* cns = cnorm_cb + ((size_t)(lcur * N_SUB + s) << 8);   // uniform -> s_load

        float bx = 1e30f, by = 1e30f;
        int   kx = 0, ky = 0;
        {
#pragma clang fp contract(off)
#pragma unroll 2
            for (int kkp = 0; kkp < N_CLUSTERS / 2; kkp++) {
                v2f cn2 = *(const v2f*)(cns + (kkp << 1));
                v2f a = (v2f){0.f, 0.f};
#pragma unroll
                for (int d = 0; d < D_SUB; d++) {
                    v2f c = *(const v2f*)(cbs + (size_t)(d * N_CLUSTERS) + (kkp << 1));
                    a = a + xs2[d] * c;          // v_pk_mul + v_pk_add, exact order
                }
                v2f dd = (xnv - twov * a) + cn2;
                if (dd.x < bx) { bx = dd.x; kx = kkp; }
                if (dd.y < by) { by = dd.y; ky = kkp; }
            }
        }
        // merge even/odd chains: strictly-better or equal-with-lower-k picks odd
        int bk = 2 * kx;
        { int kodd = 2 * ky + 1; if (by < bx || (by == bx && kodd < bk)) bk = kodd; }

        if (!done && l == lcur) { bestk = bk; done = true; }
    }
    codes[((size_t)n << 3) | s] = (unsigned char)bestk;
}

// ---------------------------------------------------------------- decode (fast): 1 line per (n,s)
__global__ __launch_bounds__(256) void pq_decode_fast(
    const float* __restrict__ cbT2, const int* __restrict__ labels,
    const unsigned char* __restrict__ codes, float* __restrict__ out)
{
    int s = blockIdx.x & 7;
    int n = (blockIdx.x >> 3) * 256 + threadIdx.x;
    int l = labels[n];
    int k = codes[(size_t)n * N_SUB + s];
    const float4* p = (const float4*)(cbT2 + ((size_t)(l * N_SUB + s) << 12) + ((size_t)k << 4));
    float4 a = p[0], b = p[1], c = p[2], d = p[3];
    float v[D_SUB] = { a.x, a.y, a.z, a.w, b.x, b.y, b.z, b.w,
                       c.x, c.y, c.z, c.w, d.x, d.y, d.z, d.w };
#pragma unroll
    for (int dd = 0; dd < D_SUB; dd++)
        out[(size_t)(s * D_SUB + dd) * N_DATA + n] = v[dd];   // coalesced
}

// ---------------------------------------------------------------- decode (fallback): strided column gather
__global__ __launch_bounds__(256) void pq_decode(
    const float* __restrict__ cb, const int* __restrict__ labels,
    const unsigned char* __restrict__ codes, float* __restrict__ out)
{
    int s = blockIdx.x & 7;
    int n = (blockIdx.x >> 3) * 256 + threadIdx.x;
    int l = labels[n];
    int k = codes[(size_t)n * N_SUB + s];
    const float* base = cb + ((size_t)(l * N_SUB + s) * D_SUB) * N_CLUSTERS + k;
#pragma unroll
    for (int dd = 0; dd < D_SUB; dd++)
        out[(size_t)(s * D_SUB + dd) * N_DATA + n] = base[(size_t)dd * N_CLUSTERS];
}

// ---------------------------------------------------------------- launcher
extern "C" void kernel_launch(void* const* d_in, const int* in_sizes, int n_in,
                              void* d_out, int out_size, void* d_ws, size_t ws_size,
                              hipStream_t stream)
{
    (void)in_sizes; (void)n_in; (void)out_size;
    const float* x   = (const float*)d_in[0];
    const float* cb  = (const float*)d_in[1];
    const float* sel = (const float*)d_in[2];
    float* out = (float*)d_out;

    int*   wsi    = (int*)d_ws;
    float* wsf    = (float*)d_ws;
    int*   labels = wsi + WS_LABELS;
    unsigned int* perm = (unsigned int*)(wsi + WS_PERM);
    int*   cnt    = wsi + WS_CNT;
    int*   cursor = wsi + WS_CURSOR;
    int*   off    = wsi + WS_OFF;
    float* cnorm  = wsf + WS_CNORM;
    float* cnsel  = wsf + WS_CNSEL;
    unsigned char* codes = (unsigned char*)(wsi + WS_CODES);

    // row-major decode codebook only if the workspace is big enough (~10.5 MiB)
    bool big = ws_size >= (size_t)(WS_CBT2 + CBT2_WORDS) * 4u;
    float* cbT2 = big ? (wsf + WS_CBT2) : (float*)nullptr;

    // permuted-gathered x (64 MiB) lives in d_out; decode overwrites it fully
    float* xg = out;

    hipLaunchKernelGGL(pq_precompute, dim3(512), dim3(256), 0, stream, cb, sel, cnorm, cnsel, cbT2, cnt);
    hipLaunchKernelGGL(pq_labels2, dim3(N_DATA / 256), dim3(256), 0, stream, x, sel, cnsel, labels, cnt);
    hipLaunchKernelGGL(pq_scan, dim3(1), dim3(64), 0, stream, cnt, off, cursor);
    hipLaunchKernelGGL(pq_scatter, dim3(N_DATA / 1024), dim3(256), 0, stream, x, labels, cursor, perm, xg);
    hipLaunchKernelGGL(pq_encode9, dim3((N_DATA / 256) * N_SUB), dim3(256), 0, stream,
                       xg, cb, cnorm, perm, codes);
    if (big)
        hipLaunchKernelGGL(pq_decode_fast, dim3((N_DATA / 256) * N_SUB), dim3(256), 0, stream,
                           cbT2, labels, codes, out);
    else
        hipLaunchKernelGGL(pq_decode, dim3((N_DATA / 256) * N_SUB), dim3(256), 0, stream,
                           cb, labels, codes, out);
}